// Round 1
// baseline (224.323 us; speedup 1.0000x reference)
//
#include <hip/hip_runtime.h>

// VQ-VAE VectorQuantizer forward: K=1024 codes, E=64, T=1024, B=64.
// inputs  d_in[0]: float32 [E, T, B]  -> x[n][e] = in[e*65536 + n], n = t*B+b
// codebook d_in[1]: float32 [K, E]
// out: [0]=vq_loss, [1 .. 4194304]=quantized [E,T,B], [4194305]=perplexity
//
// Pipeline:
//  k_ee      : ee[k] = ||e_k||^2                       (fp32)
//  k_argmin  : per row, argmin_k (ee[k] - 2 x.e_k), top-2 tracked;
//              rows with gap < 1e-6 flagged for fp64 recheck
//  k_recheck : fp64 exact argmin for flagged rows (expected ~tens of rows)
//  k_output  : gather q, write quantized, SSE partial, histogram
//  k_final   : loss + perplexity

#define KC 1024
#define ED 64
#define NR 65536            // T*B
#define NE (NR * ED)        // total elements

// ws layout in dwords:
//  [0..1023]      counts (u32)        -- zeroed each call
//  [1024]         sse (f32)           -- zeroed each call
//  [1025]         flagcnt (u32)       -- zeroed each call
//  [1088..2111]   ee (f32)
//  [2112..67647]  idx (i32)
//  [67648..133183] flaglist (u32)

__global__ __launch_bounds__(256) void k_ee(const float* __restrict__ cb,
                                            float* __restrict__ ee) {
    int k = blockIdx.x * blockDim.x + threadIdx.x;
    if (k >= KC) return;
    const float4* c4 = (const float4*)(cb + (size_t)k * ED);
    float s0 = 0.f, s1 = 0.f, s2 = 0.f, s3 = 0.f;
#pragma unroll
    for (int i = 0; i < 16; ++i) {
        float4 c = c4[i];
        s0 = fmaf(c.x, c.x, s0); s1 = fmaf(c.y, c.y, s1);
        s2 = fmaf(c.z, c.z, s2); s3 = fmaf(c.w, c.w, s3);
    }
    ee[k] = (s0 + s1) + (s2 + s3);
}

// block = 256 threads = 4 waves; block handles 64 rows, each wave does a
// 256-code K-slice; LDS merge of top-2 across the 4 slices (ascending k to
// preserve first-min tie-break, matching np.argmin).
__global__ __launch_bounds__(256) void k_argmin(
        const float* __restrict__ in, const float* __restrict__ cb,
        const float* __restrict__ ee, int* __restrict__ idx,
        unsigned* __restrict__ flagcnt, unsigned* __restrict__ flaglist) {
    __shared__ float mb[4][64];
    __shared__ float mb2[4][64];
    __shared__ int   mk[4][64];

    const int tid  = threadIdx.x;
    const int lane = tid & 63;
    const int wid  = __builtin_amdgcn_readfirstlane(tid >> 6); // wave-uniform
    const int row  = blockIdx.x * 64 + lane;

    float x[ED];
#pragma unroll
    for (int e = 0; e < ED; ++e) x[e] = in[(size_t)e * NR + row];

    const int kbase = wid * 256;
    float best = 3.4e38f, best2 = 3.4e38f;
    int bestk = kbase;

#pragma unroll 2
    for (int kk = 0; kk < 256; ++kk) {
        const int k = kbase + kk;
        const float4* c4 = (const float4*)(cb + (size_t)k * ED);
        float s0 = 0.f, s1 = 0.f, s2 = 0.f, s3 = 0.f;
#pragma unroll
        for (int e4 = 0; e4 < 16; ++e4) {
            float4 c = c4[e4];
            s0 = fmaf(c.x, x[e4 * 4 + 0], s0);
            s1 = fmaf(c.y, x[e4 * 4 + 1], s1);
            s2 = fmaf(c.z, x[e4 * 4 + 2], s2);
            s3 = fmaf(c.w, x[e4 * 4 + 3], s3);
        }
        const float s = (s0 + s1) + (s2 + s3);
        const float t = fmaf(-2.f, s, ee[k]);
        const bool c = t < best;          // strict < keeps lowest k on ties
        best2 = c ? best : fminf(best2, t);
        bestk = c ? k : bestk;
        best  = c ? t : best;
    }

    mb[wid][lane] = best; mb2[wid][lane] = best2; mk[wid][lane] = bestk;
    __syncthreads();

    if (wid == 0) {
        float b = mb[0][lane], b2 = mb2[0][lane];
        int bk = mk[0][lane];
#pragma unroll
        for (int i = 1; i < 4; ++i) {       // ascending k-slices: tie -> lower k
            const float bi = mb[i][lane], b2i = mb2[i][lane];
            const int ki = mk[i][lane];
            if (bi < b) { b2 = fminf(b, b2i); bk = ki; b = bi; }
            else        { b2 = fminf(b2, bi); }
        }
        idx[row] = bk;
        if (b2 - b < 1e-6f) {               // fp32 error bound ~5e-7 < margin
            unsigned p = atomicAdd(flagcnt, 1u);
            flaglist[p] = (unsigned)row;
        }
    }
}

// fp64 exact re-resolve of flagged rows. One block per flagged row (strided).
__global__ __launch_bounds__(256) void k_recheck(
        const float* __restrict__ in, const float* __restrict__ cb,
        int* __restrict__ idx, const unsigned* __restrict__ flagcnt,
        const unsigned* __restrict__ flaglist) {
    __shared__ float xs[ED];
    __shared__ double rb[256];
    __shared__ int    rk[256];
    const unsigned n = *flagcnt;
    const int tid = threadIdx.x;

    for (unsigned i = blockIdx.x; i < n; i += gridDim.x) {
        const unsigned row = flaglist[i];
        __syncthreads();
        if (tid < ED) xs[tid] = in[(size_t)tid * NR + row];
        __syncthreads();

        double best = 1e300; int bestk = 0;
#pragma unroll
        for (int kk = 0; kk < 4; ++kk) {
            const int k = tid * 4 + kk;
            const float* c = cb + (size_t)k * ED;
            double s = 0.0, e2 = 0.0;
            for (int e = 0; e < ED; ++e) {
                const double cv = (double)c[e];
                e2 = fma(cv, cv, e2);
                s  = fma(cv, (double)xs[e], s);
            }
            const double t = e2 - 2.0 * s;
            if (t < best || (t == best && k < bestk)) { best = t; bestk = k; }
        }
        rb[tid] = best; rk[tid] = bestk;
        __syncthreads();
        for (int off = 128; off > 0; off >>= 1) {
            if (tid < off) {
                const double ob = rb[tid + off]; const int ok = rk[tid + off];
                if (ob < rb[tid] || (ob == rb[tid] && ok < rk[tid])) {
                    rb[tid] = ob; rk[tid] = ok;
                }
            }
            __syncthreads();
        }
        if (tid == 0) idx[row] = rk[0];
        __syncthreads();
    }
}

// gather + quantized write + SSE + histogram. One thread per row.
__global__ __launch_bounds__(256) void k_output(
        const float* __restrict__ in, const float* __restrict__ cb,
        const int* __restrict__ idx, float* __restrict__ qout,
        unsigned* __restrict__ counts, float* __restrict__ sse) {
    const int n = blockIdx.x * 256 + threadIdx.x;
    const int k = idx[n];
    atomicAdd(&counts[k], 1u);
    const float* c = cb + (size_t)k * ED;
    float local = 0.f;
#pragma unroll
    for (int e = 0; e < ED; ++e) {
        const float q  = c[e];
        const float xv = in[(size_t)e * NR + n];
        qout[(size_t)e * NR + n] = q;     // quantized forward value == q
        const float d = q - xv;
        local = fmaf(d, d, local);
    }
#pragma unroll
    for (int off = 32; off > 0; off >>= 1) local += __shfl_down(local, off, 64);
    if ((threadIdx.x & 63) == 0) atomicAdd(sse, local);
}

__global__ __launch_bounds__(1024) void k_final(
        const unsigned* __restrict__ counts, const float* __restrict__ sse,
        float* __restrict__ out) {
    __shared__ float red[16];
    const int tid = threadIdx.x;
    const float p = (float)counts[tid] * (1.f / 65536.f);
    float term = p * logf(p + 1e-10f);    // p==0 -> 0 * finite = 0
#pragma unroll
    for (int off = 32; off > 0; off >>= 1) term += __shfl_down(term, off, 64);
    if ((tid & 63) == 0) red[tid >> 6] = term;
    __syncthreads();
    if (tid == 0) {
        float s = 0.f;
#pragma unroll
        for (int i = 0; i < 16; ++i) s += red[i];
        out[1 + NE] = expf(-s);                       // perplexity
        const float m = *sse * (1.f / 4194304.f);     // mean((q-x)^2)
        out[0] = fmaf(0.25f, m, m);                   // q_loss + beta*e_loss
    }
}

extern "C" void kernel_launch(void* const* d_in, const int* in_sizes, int n_in,
                              void* d_out, int out_size, void* d_ws, size_t ws_size,
                              hipStream_t stream) {
    (void)in_sizes; (void)n_in; (void)out_size; (void)ws_size;
    const float* in = (const float*)d_in[0];
    const float* cb = (const float*)d_in[1];
    float* out = (float*)d_out;

    unsigned* counts   = (unsigned*)d_ws;
    float*    sse      = (float*)d_ws + 1024;
    unsigned* flagcnt  = (unsigned*)d_ws + 1025;
    float*    ee       = (float*)d_ws + 1088;
    int*      idx      = (int*)d_ws + 2112;
    unsigned* flaglist = (unsigned*)d_ws + 2112 + NR;

    hipMemsetAsync(d_ws, 0, 4104, stream);  // counts + sse + flagcnt

    hipLaunchKernelGGL(k_ee,      dim3(4),    dim3(256),  0, stream, cb, ee);
    hipLaunchKernelGGL(k_argmin,  dim3(1024), dim3(256),  0, stream,
                       in, cb, ee, idx, flagcnt, flaglist);
    hipLaunchKernelGGL(k_recheck, dim3(64),   dim3(256),  0, stream,
                       in, cb, idx, flagcnt, flaglist);
    hipLaunchKernelGGL(k_output,  dim3(256),  dim3(256),  0, stream,
                       in, cb, idx, out + 1, counts, sse);
    hipLaunchKernelGGL(k_final,   dim3(1),    dim3(1024), 0, stream,
                       counts, sse, out);
}

// Round 4
// 165.005 us; speedup vs baseline: 1.3595x; 1.3595x over previous
//
#include <hip/hip_runtime.h>

// VQ-VAE VectorQuantizer fwd. K=1024, E=64, N=T*B=65536.
// Tiered argmin: bf16-split MFMA (gap<6e-6 flagged) -> fp32 exact
// (gap<2e-7 flagged) -> fp64 exact. Scores t = ||c||^2 - 2 x.c via
// codebook pre-scaled by -2 and ||c||^2 folded into the MFMA C-init.
// MFMA roles: A = codebook fragment, B = x fragment, so that D at
// (lane l, reg r) = score(code = t*16 + (l>>4)*4 + r, row = base + (l&15))
// per verified C/D map col=lane&15 (N), row=(lane>>4)*4+reg (M).
//
// R4 fix: ws layout had cbp/ee4p overlapping by 48KB (ee4p is 16384 dwords,
// not 4096) -> write-write race in k_pack -> pass-then-fail under graph
// replay re-validation. Layout now strictly disjoint.

#define KC 1024
#define ED 64
#define NR 65536
#define NE (NR * ED)
#define GAP1 6e-6f
#define GAP2 2e-7f

typedef __attribute__((ext_vector_type(8))) short short8;
typedef __attribute__((ext_vector_type(4))) float f32x4;

__device__ __forceinline__ unsigned short bf16rne(float f) {
    unsigned u = __builtin_bit_cast(unsigned, f);
    return (unsigned short)((u + 0x7fffu + ((u >> 16) & 1u)) >> 16);
}
__device__ __forceinline__ float bf16tof(unsigned short h) {
    return __builtin_bit_cast(float, (unsigned)h << 16);
}

// ee[k] = ||c_k||^2 (fp32) and e2d[k] (fp64)
__global__ __launch_bounds__(256) void k_prep_ee(const float* __restrict__ cb,
        float* __restrict__ ee, double* __restrict__ e2d) {
    int k = blockIdx.x * 256 + threadIdx.x;
    if (k >= KC) return;
    const float* c = cb + (size_t)k * ED;
    float s = 0.f; double sd = 0.0;
    for (int e = 0; e < ED; ++e) { float v = c[e]; s = fmaf(v, v, s); sd = fma((double)v, (double)v, sd); }
    ee[k] = s; e2d[k] = sd;
}

// Pack codebook fragments (MFMA A-operand): logical K axis per code tile =
// chunks j of -2*c: [ch e0-31 | ch e32-63 | cl e0-31 | cl e32-63 | ch e0-31 |
// ch e32-63], paired at MFMA time with x chunks [xh0|xh1|xh0|xh1|xl0|xl1].
// Element (g=l>>4, r) of chunk j <-> within-chunk k-slot g*8+r (any
// consistent bijection works: HW pairs A(g,r) with B(g,r)).
// cbp[(t*6+j)*64 + l] holds lane l's short8 for code tile t.
// ee4p C-init: reg r of lane l, tile t <-> code t*16 + (l>>4)*4 + r (M-dim).
__global__ __launch_bounds__(256) void k_pack(const float* __restrict__ cb,
        const float* __restrict__ ee, short8* __restrict__ cbp,
        f32x4* __restrict__ ee4p) {
    int u = blockIdx.x * 256 + threadIdx.x;
    if (u < 64 * 6 * 64) {
        int t = u / 384, rem = u % 384, j = rem / 64, l = rem % 64;
        int code = t * 16 + (l & 15), g = l >> 4;
        const float* c = cb + (size_t)code * ED;
        short8 o;
#pragma unroll
        for (int r = 0; r < 8; ++r) {
            int k = j * 32 + g * 8 + r;
            int e; bool lo;
            if (j < 2)      { e = k;       lo = false; }
            else if (j < 4) { e = k - 64;  lo = true;  }
            else            { e = k - 128; lo = false; }
            float m2 = -2.f * c[e];
            unsigned short h = bf16rne(m2);
            o[r] = lo ? (short)bf16rne(m2 - bf16tof(h)) : (short)h;
        }
        cbp[u] = o;
    } else if (u < 64 * 6 * 64 + 64 * 64) {
        int v = u - 64 * 6 * 64;
        int t = v >> 6, l = v & 63, g = l >> 4;
        f32x4 o;
#pragma unroll
        for (int r = 0; r < 4; ++r) o[r] = ee[t * 16 + g * 4 + r];
        ee4p[v] = o;
    }
}

// 4 waves/block, 64 rows/wave (4 rowtiles of 16), all 1024 codes per wave.
// B (x hi/lo fragments) resident in VGPRs; A streamed from packed codebook.
__global__ __launch_bounds__(256) void k_argmin_mfma(
        const float* __restrict__ in, const short8* __restrict__ cbp,
        const f32x4* __restrict__ ee4p, int* __restrict__ idx,
        unsigned* __restrict__ flagcnt, unsigned* __restrict__ flaglist) {
    const int tid = threadIdx.x;
    const int l = tid & 63;
    const int wid = tid >> 6;
    const int g = l >> 4;
    const int col = l & 15;
    const int rowBase = blockIdx.x * 256 + wid * 64;

    short8 xh[4][2], xl[4][2];
#pragma unroll
    for (int rt = 0; rt < 4; ++rt) {
        const int row = rowBase + rt * 16 + col;
#pragma unroll
        for (int h = 0; h < 2; ++h) {
            short8 H, L;
#pragma unroll
            for (int r = 0; r < 8; ++r) {
                const int e = h * 32 + g * 8 + r;
                const float x = in[(size_t)e * NR + row];
                const unsigned short hb = bf16rne(x);
                H[r] = (short)hb;
                L[r] = (short)bf16rne(x - bf16tof(hb));
            }
            xh[rt][h] = H; xl[rt][h] = L;
        }
    }

    float best[4]  = {3.4e38f, 3.4e38f, 3.4e38f, 3.4e38f};
    float best2[4] = {3.4e38f, 3.4e38f, 3.4e38f, 3.4e38f};
    int bestk[4] = {0, 0, 0, 0};

#pragma unroll 2
    for (int t = 0; t < 64; ++t) {
        const short8* bp = cbp + t * 384 + l;
        const short8 b0 = bp[0], b1 = bp[64], b2 = bp[128],
                     b3 = bp[192], b4 = bp[256], b5 = bp[320];
        const f32x4 e4 = ee4p[t * 64 + l];
#pragma unroll
        for (int rt = 0; rt < 4; ++rt) {
            f32x4 acc = e4;
            // A = codebook chunk, B = x chunk (pairing by identical (g,r) map)
            acc = __builtin_amdgcn_mfma_f32_16x16x32_bf16(b0, xh[rt][0], acc, 0, 0, 0);
            acc = __builtin_amdgcn_mfma_f32_16x16x32_bf16(b1, xh[rt][1], acc, 0, 0, 0);
            acc = __builtin_amdgcn_mfma_f32_16x16x32_bf16(b2, xh[rt][0], acc, 0, 0, 0);
            acc = __builtin_amdgcn_mfma_f32_16x16x32_bf16(b3, xh[rt][1], acc, 0, 0, 0);
            acc = __builtin_amdgcn_mfma_f32_16x16x32_bf16(b4, xl[rt][0], acc, 0, 0, 0);
            acc = __builtin_amdgcn_mfma_f32_16x16x32_bf16(b5, xl[rt][1], acc, 0, 0, 0);
#pragma unroll
            for (int r = 0; r < 4; ++r) {
                const float v = acc[r];
                const int k = t * 16 + g * 4 + r;   // M-dim: code = (l>>4)*4+r
                const bool c = v < best[rt];
                best2[rt] = c ? best[rt] : fminf(best2[rt], v);
                bestk[rt] = c ? k : bestk[rt];
                best[rt]  = c ? v : best[rt];
            }
        }
    }

#pragma unroll
    for (int rt = 0; rt < 4; ++rt) {
        float b = best[rt], b2 = best2[rt]; int k = bestk[rt];
#pragma unroll
        for (int sh = 16; sh <= 32; sh <<= 1) {   // merge g-groups: l^16, l^32
            const float ob  = __shfl_xor(b, sh, 64);
            const float ob2 = __shfl_xor(b2, sh, 64);
            const int   ok  = __shfl_xor(k, sh, 64);
            if (ob < b || (ob == b && ok < k)) { b2 = fminf(b, ob2); k = ok; b = ob; }
            else b2 = fminf(b2, ob);
        }
        if (g == 0) {
            const int row = rowBase + rt * 16 + col;
            idx[row] = k;
            if (b2 - b < GAP1) {
                const unsigned p = atomicAdd(flagcnt, 1u);
                flaglist[p] = (unsigned)row;
            }
        }
    }
}

// fp32 exact argmin for tier-1 flagged rows; one wave per row.
__global__ __launch_bounds__(256) void k_exact32(
        const float* __restrict__ in, const float* __restrict__ cb,
        const float* __restrict__ ee, int* __restrict__ idx,
        const unsigned* __restrict__ flagcnt, const unsigned* __restrict__ flaglist,
        unsigned* __restrict__ flagcnt2, unsigned* __restrict__ flaglist2) {
    const unsigned nf = *flagcnt;
    const int l = threadIdx.x & 63;
    const unsigned wave = blockIdx.x * 4u + (unsigned)(threadIdx.x >> 6);
    const unsigned nwave = gridDim.x * 4u;
    for (unsigned i = wave; i < nf; i += nwave) {
        const int row = (int)flaglist[i];
        float x[ED];
#pragma unroll
        for (int e = 0; e < ED; ++e) x[e] = in[(size_t)e * NR + row];
        float best = 3.4e38f, best2 = 3.4e38f; int bestk = 0;
        for (int ci = 0; ci < 16; ++ci) {
            const int k = ci * 64 + l;              // per-lane ascending k
            const float4* c4 = (const float4*)(cb + (size_t)k * ED);
            float s0 = 0.f, s1 = 0.f, s2 = 0.f, s3 = 0.f;
#pragma unroll
            for (int e4 = 0; e4 < 16; ++e4) {
                float4 c = c4[e4];
                s0 = fmaf(c.x, x[e4 * 4 + 0], s0);
                s1 = fmaf(c.y, x[e4 * 4 + 1], s1);
                s2 = fmaf(c.z, x[e4 * 4 + 2], s2);
                s3 = fmaf(c.w, x[e4 * 4 + 3], s3);
            }
            const float t = fmaf(-2.f, (s0 + s1) + (s2 + s3), ee[k]);
            const bool c = t < best;
            best2 = c ? best : fminf(best2, t);
            bestk = c ? k : bestk;
            best  = c ? t : best;
        }
#pragma unroll
        for (int sh = 1; sh < 64; sh <<= 1) {
            const float ob  = __shfl_xor(best, sh, 64);
            const float ob2 = __shfl_xor(best2, sh, 64);
            const int   ok  = __shfl_xor(bestk, sh, 64);
            if (ob < best || (ob == best && ok < bestk)) { best2 = fminf(best, ob2); bestk = ok; best = ob; }
            else best2 = fminf(best2, ob);
        }
        if (l == 0) {
            idx[row] = bestk;
            if (best2 - best < GAP2) {
                const unsigned p = atomicAdd(flagcnt2, 1u);
                flaglist2[p] = (unsigned)row;
            }
        }
    }
}

// fp64 exact argmin for tier-2 flagged rows; one wave per row.
__global__ __launch_bounds__(256) void k_exact64(
        const float* __restrict__ in, const float* __restrict__ cb,
        const double* __restrict__ e2d, int* __restrict__ idx,
        const unsigned* __restrict__ flagcnt2, const unsigned* __restrict__ flaglist2) {
    const unsigned nf = *flagcnt2;
    const int l = threadIdx.x & 63;
    const unsigned wave = blockIdx.x * 4u + (unsigned)(threadIdx.x >> 6);
    const unsigned nwave = gridDim.x * 4u;
    for (unsigned i = wave; i < nf; i += nwave) {
        const int row = (int)flaglist2[i];
        float x[ED];
#pragma unroll
        for (int e = 0; e < ED; ++e) x[e] = in[(size_t)e * NR + row];
        double best = 1e300; int bestk = 0;
        for (int ci = 0; ci < 16; ++ci) {
            const int k = ci * 64 + l;
            const float* c = cb + (size_t)k * ED;
            double s = 0.0;
            for (int e = 0; e < ED; ++e) s = fma((double)c[e], (double)x[e], s);
            const double t = fma(-2.0, s, e2d[k]);
            if (t < best) { best = t; bestk = k; }
        }
        for (int sh = 1; sh < 64; sh <<= 1) {
            const double ob = __shfl_xor(best, sh, 64);
            const int   ok  = __shfl_xor(bestk, sh, 64);
            if (ob < best || (ob == best && ok < bestk)) { best = ob; bestk = ok; }
        }
        if (l == 0) idx[row] = bestk;
    }
}

// gather + quantized write + SSE (fp64 accum) + histogram
__global__ __launch_bounds__(256) void k_output(
        const float* __restrict__ in, const float* __restrict__ cb,
        const int* __restrict__ idx, float* __restrict__ qout,
        unsigned* __restrict__ counts, double* __restrict__ sse) {
    const int n = blockIdx.x * 256 + threadIdx.x;
    const int k = idx[n];
    atomicAdd(&counts[k], 1u);
    const float* c = cb + (size_t)k * ED;
    float local = 0.f;
#pragma unroll
    for (int e = 0; e < ED; ++e) {
        const float q  = c[e];
        const float xv = in[(size_t)e * NR + n];
        qout[(size_t)e * NR + n] = q;
        const float d = q - xv;
        local = fmaf(d, d, local);
    }
    double ld = (double)local;
#pragma unroll
    for (int off = 32; off > 0; off >>= 1) ld += __shfl_down(ld, off, 64);
    if ((threadIdx.x & 63) == 0) atomicAdd(sse, ld);
}

__global__ __launch_bounds__(1024) void k_final(const unsigned* __restrict__ counts,
        const double* __restrict__ sse, float* __restrict__ out) {
    __shared__ double red[16];
    const int tid = threadIdx.x;
    const double p = (double)counts[tid] * (1.0 / 65536.0);
    double term = p * log(p + 1e-10);
#pragma unroll
    for (int off = 32; off > 0; off >>= 1) term += __shfl_down(term, off, 64);
    if ((tid & 63) == 0) red[tid >> 6] = term;
    __syncthreads();
    if (tid == 0) {
        double s = 0.0;
        for (int i = 0; i < 16; ++i) s += red[i];
        out[1 + NE] = (float)exp(-s);                 // perplexity
        const double m = *sse * (1.0 / 4194304.0);    // mean((q-x)^2)
        out[0] = (float)(1.25 * m);                   // (1+beta)*m
    }
}

extern "C" void kernel_launch(void* const* d_in, const int* in_sizes, int n_in,
                              void* d_out, int out_size, void* d_ws, size_t ws_size,
                              hipStream_t stream) {
    (void)in_sizes; (void)n_in; (void)out_size; (void)ws_size;
    const float* in = (const float*)d_in[0];
    const float* cb = (const float*)d_in[1];
    float* out = (float*)d_out;

    // ws layout (dword offsets) -- STRICTLY DISJOINT:
    //  [0,1024)        counts (u32)
    //  [1024]          flagcnt    [1025] flagcnt2
    //  [1026,1028)     sse (f64, byte 4104, 8B-aligned)
    //  [1088,2112)     ee (f32)
    //  [2112,4160)     e2d (f64, byte 8448)
    //  [4160,102464)   cbp: 24576 short8 (byte 16640, 16B-aligned)
    //  [102464,118848) ee4p: 4096 f32x4 (byte 409856, 16B-aligned)
    //  [118848,184384) idx (i32)
    //  [184384,249920) flaglist
    //  [249920,315456) flaglist2   -- total 1,261,824 B
    unsigned* counts    = (unsigned*)d_ws;
    unsigned* flagcnt   = (unsigned*)d_ws + 1024;
    unsigned* flagcnt2  = (unsigned*)d_ws + 1025;
    double*   sse       = (double*)((char*)d_ws + 4104);
    float*    ee        = (float*)d_ws + 1088;
    double*   e2d       = (double*)((char*)d_ws + 8448);
    short8*   cbp       = (short8*)((float*)d_ws + 4160);
    f32x4*    ee4p      = (f32x4*)((float*)d_ws + 102464);
    int*      idx       = (int*)d_ws + 118848;
    unsigned* flaglist  = (unsigned*)d_ws + 184384;
    unsigned* flaglist2 = (unsigned*)d_ws + 249920;

    hipMemsetAsync(d_ws, 0, 4112, stream);  // counts + flagcnts + sse

    hipLaunchKernelGGL(k_prep_ee,    dim3(4),   dim3(256),  0, stream, cb, ee, e2d);
    hipLaunchKernelGGL(k_pack,       dim3(112), dim3(256),  0, stream, cb, ee, cbp, ee4p);
    hipLaunchKernelGGL(k_argmin_mfma,dim3(256), dim3(256),  0, stream,
                       in, cbp, ee4p, idx, flagcnt, flaglist);
    hipLaunchKernelGGL(k_exact32,    dim3(128), dim3(256),  0, stream,
                       in, cb, ee, idx, flagcnt, flaglist, flagcnt2, flaglist2);
    hipLaunchKernelGGL(k_exact64,    dim3(128), dim3(256),  0, stream,
                       in, cb, e2d, idx, flagcnt2, flaglist2);
    hipLaunchKernelGGL(k_output,     dim3(256), dim3(256),  0, stream,
                       in, cb, idx, out + 1, counts, sse);
    hipLaunchKernelGGL(k_final,      dim3(1),   dim3(1024), 0, stream,
                       counts, sse, out);
}